// Round 1
// baseline (14.365 us; speedup 1.0000x reference)
//
#include <hip/hip_runtime.h>

// LatticeSnake: sparse re-formulation.
// Reference scatters 127 points/sample into a 323^3 lattice then slices 64
// 7x7x7 windows. We instead gather: out[b,n,u,v,w] = sum of point values whose
// (idx+HALF) index equals idx2[b,n]+(u,v,w). Masked points -> sentinel (ref
// sends them to LP=323 which can never land in a window: max coord 252+6=258).

#define NN 64
#define KK 7
#define HALF_ 3
#define NPTS (2*NN - 1)   // 127
#define WIN (KK*KK*KK)    // 343
#define BB 2

__global__ __launch_bounds__(384) void LatticeSnake_kernel(
    const float* __restrict__ acids,            // B*N f32
    const unsigned char* __restrict__ mask_raw, // layout detected on-device
    const int* __restrict__ idx,                // B*N*3 i32
    float* __restrict__ out)                    // B*N*343 f32
{
    __shared__ int   sPx[NPTS], sPy[NPTS], sPz[NPTS];
    __shared__ float sPv[NPTS];
    __shared__ int   sIdx2[NN][3];
    __shared__ float sAcid[NN];
    __shared__ int   sMask[NN];
    __shared__ int   sNZ0, sNZoff;

    const int b = blockIdx.x >> 6;   // / N
    const int n = blockIdx.x & 63;   // % N
    const int t = threadIdx.x;

    // ---- mask dtype/layout detection ----
    // First 128 bytes are in-bounds for every candidate layout (128 elems).
    //   int32 0/1  : nonzero bytes only at off%4==0          -> NZ0=1, NZoff=0
    //   f32 0/1.0  : nonzero bytes only at off%4 in {2,3}    -> NZ0=0, NZoff=1
    //   u8 bool    : ~90% ones everywhere                    -> NZ0=1, NZoff=1
    if (t == 0) { sNZ0 = 0; sNZoff = 0; }
    __syncthreads();
    if (t < 128) {
        unsigned char byte = mask_raw[t];
        if (byte) {
            if ((t & 3) == 0) sNZ0 = 1; else sNZoff = 1;
        }
    }
    __syncthreads();
    const bool isU8 = (sNZ0 && sNZoff);

    // ---- load per-sample atoms ----
    if (t < NN) {
        const int base = (b * NN + t) * 3;
        sIdx2[t][0] = 2 * (idx[base + 0] + (NN - 1));
        sIdx2[t][1] = 2 * (idx[base + 1] + (NN - 1));
        sIdx2[t][2] = 2 * (idx[base + 2] + (NN - 1));
        sAcid[t] = acids[b * NN + t];
        int m;
        if (isU8) m = mask_raw[b * NN + t] != 0;
        else      m = ((const unsigned int*)mask_raw)[b * NN + t] != 0u; // int32 or f32 bits
        sMask[t] = m;
    }
    __syncthreads();

    // ---- build the 127 scatter points (atoms + midpoints) ----
    if (t < NPTS) {
        int px, py, pz, m; float v;
        if (t < NN) {
            px = sIdx2[t][0]; py = sIdx2[t][1]; pz = sIdx2[t][2];
            v = sAcid[t]; m = sMask[t];
        } else {
            const int i = t - NN; // 0..62
            px = (sIdx2[i][0] + sIdx2[i + 1][0]) >> 1; // sums of evens: exact
            py = (sIdx2[i][1] + sIdx2[i + 1][1]) >> 1;
            pz = (sIdx2[i][2] + sIdx2[i + 1][2]) >> 1;
            v = sAcid[i] + sAcid[i + 1] + 1.0f;
            m = sMask[i + 1];
        }
        sPx[t] = m ? px + HALF_ : -10000;  // masked -> unmatchable sentinel
        sPy[t] = m ? py + HALF_ : -10000;
        sPz[t] = m ? pz + HALF_ : -10000;
        sPv[t] = v;
    }
    __syncthreads();

    // ---- gather one window element per thread (deterministic) ----
    if (t < WIN) {
        const int u = t / 49, rem = t % 49, v = rem / 7, w = rem % 7;
        const int tx = sIdx2[n][0] + u;
        const int ty = sIdx2[n][1] + v;
        const int tz = sIdx2[n][2] + w;
        float acc = 0.0f;
        for (int j = 0; j < NPTS; ++j) {
            const bool hit = (sPx[j] == tx) && (sPy[j] == ty) && (sPz[j] == tz);
            acc += hit ? sPv[j] : 0.0f;   // LDS broadcast reads, no conflicts
        }
        out[blockIdx.x * WIN + t] = sMask[n] ? acc : 0.0f;
    }
}

extern "C" void kernel_launch(void* const* d_in, const int* in_sizes, int n_in,
                              void* d_out, int out_size, void* d_ws, size_t ws_size,
                              hipStream_t stream) {
    const float*         acids = (const float*)d_in[0];
    const unsigned char* mask  = (const unsigned char*)d_in[1];
    const int*           idx   = (const int*)d_in[2];
    float*               out   = (float*)d_out;

    LatticeSnake_kernel<<<BB * NN, 384, 0, stream>>>(acids, mask, idx, out);
}

// Round 2
// 9.710 us; speedup vs baseline: 1.4794x; 1.4794x over previous
//
#include <hip/hip_runtime.h>

// LatticeSnake: sparse gather with bbox pre-filter.
// out[b,n,u,v,w] = sum of point values whose (idx2+HALF) coord == idx2[b,n]+(u,v,w).
// 127 points/sample; expected hits per 7^3 window ~1-3, so filter+compact first
// (ballot-based, deterministic order), then each of 343 threads matches one
// packed relative key (dx*49+dy*7+dz == threadIdx) against the short list.

#define NN 64
#define KK 7
#define HALF_ 3
#define NPTS (2*NN - 1)   // 127
#define WIN (KK*KK*KK)    // 343
#define BB 2

#define ALIGNED_MASK 0x1111111111111111ULL  // lanes %4 == 0

__global__ __launch_bounds__(384) void LatticeSnake_kernel(
    const float* __restrict__ acids,            // B*N f32
    const unsigned char* __restrict__ mask_raw, // layout detected on-device
    const int* __restrict__ idx,                // B*N*3 i32
    float* __restrict__ out)                    // B*N*343 f32
{
    __shared__ int   sIdx2[NN][3];
    __shared__ float sAcid[NN];
    __shared__ unsigned long long sBM[2];  // mask-byte ballots (dtype detect)
    __shared__ unsigned long long sWM[2];  // bbox-hit ballots (compaction)
    __shared__ int   sCK[NPTS];            // compacted relative keys
    __shared__ float sCV[NPTS];            // compacted values
    __shared__ int   sCount;
    __shared__ int   sMaskN;

    const int b = blockIdx.x >> 6;   // / N
    const int n = blockIdx.x & 63;   // % N
    const int t = threadIdx.x;
    const int lane = t & 63;
    const int wid  = t >> 6;

    // ---- Region 1: atom loads + mask dtype detection (independent) ----
    if (t < 128) {
        // dtype detect from first 128 BYTES (in-bounds for all layouts):
        //   int32 0/1 : nonzero bytes only at off%4==0
        //   f32 0/1.0 : nonzero bytes only at off%4 in {2,3}
        //   u8 bool   : nonzero bytes at both
        unsigned long long bm = __ballot(mask_raw[t] != 0);
        if (lane == 0) sBM[wid] = bm;
    }
    if (t < NN) {
        const int base = (b * NN + t) * 3;
        sIdx2[t][0] = 2 * (idx[base + 0] + (NN - 1));
        sIdx2[t][1] = 2 * (idx[base + 1] + (NN - 1));
        sIdx2[t][2] = 2 * (idx[base + 2] + (NN - 1));
        sAcid[t] = acids[b * NN + t];
    }
    __syncthreads();

    const unsigned long long bmAll = sBM[0] | sBM[1];
    const bool isU8 = (bmAll & ALIGNED_MASK) && (bmAll & ~ALIGNED_MASK);

    // window base (no HALF on targets; points carry +HALF)
    const int wx = sIdx2[n][0], wy = sIdx2[n][1], wz = sIdx2[n][2];

    // ---- Region 2: build points, bbox test, ballot ----
    unsigned long long pm = 0ULL;
    bool pred = false;
    int rk = 0; float val = 0.0f;
    if (t < NPTS) {
        int px, py, pz;
        const int me = (t < NN) ? t : (t - NN + 1);   // mask element for this point
        if (t < NN) {
            px = sIdx2[t][0]; py = sIdx2[t][1]; pz = sIdx2[t][2];
            val = sAcid[t];
        } else {
            const int i = t - NN; // 0..62
            px = (sIdx2[i][0] + sIdx2[i + 1][0]) >> 1; // sums of evens: exact
            py = (sIdx2[i][1] + sIdx2[i + 1][1]) >> 1;
            pz = (sIdx2[i][2] + sIdx2[i + 1][2]) >> 1;
            val = sAcid[i] + sAcid[i + 1] + 1.0f;
        }
        int m;
        if (isU8) m = mask_raw[b * NN + me] != 0;
        else      m = ((const unsigned int*)mask_raw)[b * NN + me] != 0u;
        const int dx = px + HALF_ - wx;
        const int dy = py + HALF_ - wy;
        const int dz = pz + HALF_ - wz;
        pred = m && ((unsigned)dx <= 6u) && ((unsigned)dy <= 6u) && ((unsigned)dz <= 6u);
        rk = dx * 49 + dy * 7 + dz;
        pm = __ballot(pred);
        if (lane == 0) sWM[wid] = pm;
    }
    __syncthreads();

    // ---- Region 3: deterministic compaction (t-ascending order) ----
    if (t < NPTS && pred) {
        const int base = wid ? __popcll(sWM[0]) : 0;
        const int pos  = base + __popcll(pm & ((1ULL << lane) - 1ULL));
        sCK[pos] = rk;
        sCV[pos] = val;
    }
    if (t == 0) {
        sCount = __popcll(sWM[0]) + __popcll(sWM[1]);
        int m;
        if (isU8) m = mask_raw[b * NN + n] != 0;
        else      m = ((const unsigned int*)mask_raw)[b * NN + n] != 0u;
        sMaskN = m;
    }
    __syncthreads();

    // ---- Region 4: gather (count expected 1-3) ----
    if (t < WIN) {
        const int cnt = sCount;
        float acc = 0.0f;
        for (int j = 0; j < cnt; ++j) {
            acc += (sCK[j] == t) ? sCV[j] : 0.0f;  // broadcast LDS reads
        }
        out[blockIdx.x * WIN + t] = sMaskN ? acc : 0.0f;
    }
}

extern "C" void kernel_launch(void* const* d_in, const int* in_sizes, int n_in,
                              void* d_out, int out_size, void* d_ws, size_t ws_size,
                              hipStream_t stream) {
    const float*         acids = (const float*)d_in[0];
    const unsigned char* mask  = (const unsigned char*)d_in[1];
    const int*           idx   = (const int*)d_in[2];
    float*               out   = (float*)d_out;

    LatticeSnake_kernel<<<BB * NN, 384, 0, stream>>>(acids, mask, idx, out);
}

// Round 3
// 9.704 us; speedup vs baseline: 1.4804x; 1.0006x over previous
//
#include <hip/hip_runtime.h>

// LatticeSnake: sparse gather, single-wave blocks.
// out[b,n,u,v,w] = sum of point values whose (idx2+HALF) coord == idx2[b,n]+(u,v,w).
// One 64-lane wave per (b,n) window. Atoms in registers; midpoints via shfl_down;
// bbox-filter + ballot-compact the ~1-3 hits into LDS; 6 output cells per lane.

#define NN 64
#define HALF_ 3
#define NPTS (2*NN - 1)   // 127
#define WIN (7*7*7)       // 343
#define BB 2

__global__ __launch_bounds__(64) void LatticeSnake_kernel(
    const float* __restrict__ acids,            // B*N f32
    const unsigned char* __restrict__ mask_raw, // layout detected on-device
    const int* __restrict__ idx,                // B*N*3 i32
    float* __restrict__ out)                    // B*N*343 f32
{
    __shared__ int   sCK[NPTS];   // compacted relative keys
    __shared__ float sCV[NPTS];   // compacted values

    const int b = blockIdx.x >> 6;   // / N
    const int n = blockIdx.x & 63;   // % N
    const int lane = threadIdx.x;

    // ---- upfront independent loads ----
    const int abase = b * NN + lane;
    const int ibase = abase * 3;
    const int ix = idx[ibase + 0];
    const int iy = idx[ibase + 1];
    const int iz = idx[ibase + 2];
    const float av = acids[abase];
    // detection sample: bytes 2*lane, 2*lane+1 (first 128 B, in-bounds all layouts)
    const unsigned short det2 = ((const unsigned short*)mask_raw)[lane];
    // speculative u8 mask (offset <=127, in-bounds for all layouts)
    const unsigned char mbyte = mask_raw[abase];

    // ---- mask dtype detection ----
    //   int32 0/1 : nonzero bytes only at off%4==0
    //   f32 0/1.0 : nonzero bytes only at off%4 in {2,3}
    //   u8 bool   : nonzero bytes at both
    const unsigned long long bm_lo = __ballot((det2 & 0xFF) != 0);   // offsets 2*lane
    const unsigned long long bm_hi = __ballot((det2 >> 8) != 0);     // offsets 2*lane+1
    const unsigned long long aligned_nz = bm_lo & 0x5555555555555555ULL; // off%4==0
    const unsigned long long nonal_nz   = (bm_lo & 0xAAAAAAAAAAAAAAAAULL) | bm_hi;
    const bool isU8 = (aligned_nz != 0ULL) && (nonal_nz != 0ULL);

    int m;
    if (isU8) m = (mbyte != 0);                                      // no extra load
    else      m = (((const unsigned int*)mask_raw)[abase] != 0u);    // i32 or f32 bits

    // idx2 (even ints)
    const int x2 = 2 * (ix + (NN - 1));
    const int y2 = 2 * (iy + (NN - 1));
    const int z2 = 2 * (iz + (NN - 1));

    // neighbor atom (lane+1) for midpoint i=lane
    const int   xn = __shfl_down(x2, 1);
    const int   yn = __shfl_down(y2, 1);
    const int   zn = __shfl_down(z2, 1);
    const float an = __shfl_down(av, 1);
    const int   mn = __shfl_down(m, 1);

    // window base = idx2[n] (points carry the +HALF)
    const int wx = __shfl(x2, n);
    const int wy = __shfl(y2, n);
    const int wz = __shfl(z2, n);
    const int maskN = __shfl(m, n);

    // point t=lane (atom)
    const int dx0 = x2 + HALF_ - wx, dy0 = y2 + HALF_ - wy, dz0 = z2 + HALF_ - wz;
    const bool pred0 = m && ((unsigned)dx0 <= 6u) && ((unsigned)dy0 <= 6u) && ((unsigned)dz0 <= 6u);
    const int rk0 = dx0 * 49 + dy0 * 7 + dz0;

    // point t=64+lane (midpoint i=lane), valid lane<63; sums of evens: exact
    const int mx = (x2 + xn) >> 1, my = (y2 + yn) >> 1, mz = (z2 + zn) >> 1;
    const float mv = av + an + 1.0f;
    const int dx1 = mx + HALF_ - wx, dy1 = my + HALF_ - wy, dz1 = mz + HALF_ - wz;
    const bool pred1 = (lane < NN - 1) && mn &&
                       ((unsigned)dx1 <= 6u) && ((unsigned)dy1 <= 6u) && ((unsigned)dz1 <= 6u);
    const int rk1 = dx1 * 49 + dy1 * 7 + dz1;

    // ---- deterministic ballot compaction (t-ascending: atoms then midpoints) ----
    const unsigned long long m0 = __ballot(pred0);
    const unsigned long long m1 = __ballot(pred1);
    const unsigned long long below = (1ULL << lane) - 1ULL;  // lane<=63: ok
    if (pred0) {
        const int p = __popcll(m0 & below);
        sCK[p] = rk0; sCV[p] = av;
    }
    if (pred1) {
        const int p = __popcll(m0) + __popcll(m1 & below);
        sCK[p] = rk1; sCV[p] = mv;
    }
    const int cnt = __popcll(m0) + __popcll(m1);

    __syncthreads();  // single wave: compiles to a cheap fence

    // ---- gather: 6 cells per lane, broadcast LDS reads of the short list ----
    float a0 = 0.f, a1 = 0.f, a2 = 0.f, a3 = 0.f, a4 = 0.f, a5 = 0.f;
    for (int j = 0; j < cnt; ++j) {
        const int   k = sCK[j];
        const float v = sCV[j];
        a0 += (k == lane      ) ? v : 0.f;
        a1 += (k == lane +  64) ? v : 0.f;
        a2 += (k == lane + 128) ? v : 0.f;
        a3 += (k == lane + 192) ? v : 0.f;
        a4 += (k == lane + 256) ? v : 0.f;
        a5 += (k == lane + 320) ? v : 0.f;
    }
    if (!maskN) { a0 = a1 = a2 = a3 = a4 = a5 = 0.f; }

    float* o = out + blockIdx.x * WIN;
    o[lane      ] = a0;
    o[lane +  64] = a1;
    o[lane + 128] = a2;
    o[lane + 192] = a3;
    o[lane + 256] = a4;
    if (lane + 320 < WIN) o[lane + 320] = a5;
}

extern "C" void kernel_launch(void* const* d_in, const int* in_sizes, int n_in,
                              void* d_out, int out_size, void* d_ws, size_t ws_size,
                              hipStream_t stream) {
    const float*         acids = (const float*)d_in[0];
    const unsigned char* mask  = (const unsigned char*)d_in[1];
    const int*           idx   = (const int*)d_in[2];
    float*               out   = (float*)d_out;

    LatticeSnake_kernel<<<BB * NN, 64, 0, stream>>>(acids, mask, idx, out);
}